// Round 2
// baseline (101.039 us; speedup 1.0000x reference)
//
#include <hip/hip_runtime.h>
#include <math.h>

// Round 13: identical to R12 (resubmit — R12 bench died with "MI355X container
// failed twice", an infra failure; kernel never ran). R12 = R11 + LDS-staged
// fp16 input slab.
// Theory: kernel (~9us of the 100.7us metric; rest is 2x ~45us harness poison
// fills) is latency/issue-bound in phase 0: 4x redundant global loads (24
// dwordx4/thread, 16 distinct segments per wave-instr) and 4x redundant
// f32->f16 converts, with HBM latency on the cvt->fma critical path.
// Fix: block's input is one contiguous 24.6KB slab (rows gi*8..gi*8+7, all
// 256 cols). Stage it cooperatively: 6 perfectly-coalesced float4 loads per
// thread -> convert to fp16 ONCE -> packed fp16 slab in LDS (12.3KB). Lift
// then reads 3x ds_read_b128 per row (node stride 48B = 12 dwords tiles all
// 32 banks; row-pair 2-way + dq same-addr broadcast are free).
// Everything after barrier 1 is identical to R11 (verified passing).
// Frag layouts (verified R6-R11): A[m=lane&15][k=(lane>>4)*8+j],
// B[k=(lane>>4)*8+j][n=lane&15], D: row=(lane>>4)*4+reg, col=lane&15.

typedef _Float16 h8 __attribute__((ext_vector_type(8)));
typedef _Float16 h4 __attribute__((ext_vector_type(4)));
typedef _Float16 h2 __attribute__((ext_vector_type(2)));
typedef float    f4 __attribute__((ext_vector_type(4)));

// LDS strides (fp16 elems; byte stride %16==0)
constexpr int SVH = 104;  // V  [32][96]   -> H1 [32][64] (S1H)
constexpr int SCH = 136;  // C  [32][128]  -> H2 [32][32] (S2H)
constexpr int S1H = 72;
constexpr int S2H = 40;

__device__ __forceinline__ h8 bfrag(const float* __restrict__ W, int N, int k0, int n)
{
    h8 r;
    #pragma unroll
    for (int j = 0; j < 8; ++j)
        r[j] = (_Float16)W[(k0 + j) * N + n];
    return r;
}

__device__ __forceinline__ h2 h2max_x4(h2 a) {   // elementwise max with lane^4
    int b;
    __builtin_memcpy(&b, &a, 4);
    b = __shfl_xor(b, 4);
    h2 o;
    __builtin_memcpy(&o, &b, 4);
    return __builtin_elementwise_max(a, o);
}

__global__ __launch_bounds__(256, 4)
void flatnet_fused(const float* __restrict__ pgi,
                   const float* __restrict__ Wl, const float* __restrict__ bl,
                   const float* __restrict__ Wc, const float* __restrict__ bc,
                   const float* __restrict__ W1, const float* __restrict__ b1,
                   const float* __restrict__ W2, const float* __restrict__ b2,
                   const float* __restrict__ W3, const float* __restrict__ b3,
                   const float* __restrict__ W4, const float* __restrict__ b4,
                   float* __restrict__ out)
{
    __shared__ __align__(16) _Float16 sP[8 * 256 * 3];   // fp16 slab, 12288 B
    __shared__ __align__(16) _Float16 sV[32 * SVH];      // V -> H1
    __shared__ __align__(16) _Float16 sC[32 * SCH];      // C -> H2

    const int t    = threadIdx.x;
    const int blk  = blockIdx.x;
    const int lane = t & 63;
    const int wv   = t >> 6;        // 0..3
    const int l15  = lane & 15;
    const int lq   = lane >> 4;     // 0..3
    const int k8   = lq * 8;

    // ===== Stage: slab f32 -> fp16 in LDS, coalesced, converted once =====
    // Block covers nodes gn = blk*32 + ln; since blk*32 is 32-aligned,
    // gj = ln (0..31) and gi is block-uniform. Slab = rows gi*8..gi*8+7,
    // cols 0..255: 6144 contiguous floats starting at (b*65536 + gi*2048)*3.
    {
        const int gn0 = blk * 32;
        const int b0  = gn0 >> 10;
        const int gi  = (gn0 & 1023) >> 5;
        const float* __restrict__ slab =
            pgi + ((size_t)b0 * 65536 + (size_t)gi * 2048) * 3;
        #pragma unroll
        for (int i = 0; i < 6; ++i) {
            const float4 v = *(const float4*)(slab + i * 1024 + t * 4);
            h4 o;
            o[0] = (_Float16)v.x;
            o[1] = (_Float16)v.y;
            o[2] = (_Float16)v.z;
            o[3] = (_Float16)v.w;
            *(h4*)&sP[i * 1024 + t * 4] = o;   // byte addr i*2048 + t*8: 2-way free
        }
    }

    // -- build P1 B-frags + bias now (consumed after barrier 1; hidden by lift)
    h8 Bf1[2][3];
    #pragma unroll
    for (int nn = 0; nn < 2; ++nn)
        #pragma unroll
        for (int kq = 0; kq < 3; ++kq)
            Bf1[nn][kq] = bfrag(Wc, 128, kq*32 + k8, (wv*2 + nn)*16 + l15);
    float bcv[2];
    bcv[0] = bc[(wv*2 + 0)*16 + l15];
    bcv[1] = bc[(wv*2 + 1)*16 + l15];

    __syncthreads();   // barrier 0: fp16 slab ready

    // ===== Phase 0: packed-fp16 lift (3->32) + ring-group max, leaky after =====
    // 8 threads/node: q&3 = dim-quarter (4 h2 pairs), q>>2 = mirrored row-half
    // (GT[7-r]==GT[r]). Points now come pre-converted from sP.
    {
        const int ln = t >> 3;          // local node 0..31 (== gj)
        const int q  = t & 7;
        const int dq = (q & 3) * 8;
        const int h  = q >> 2;

        h2 w0p[4], w1p[4], w2p[4], bbp[4];
        #pragma unroll
        for (int d2 = 0; d2 < 4; ++d2) {
            const int dd = dq + d2*2;
            w0p[d2] = h2{(_Float16)Wl[dd],      (_Float16)Wl[dd + 1]};
            w1p[d2] = h2{(_Float16)Wl[32 + dd], (_Float16)Wl[32 + dd + 1]};
            w2p[d2] = h2{(_Float16)Wl[64 + dd], (_Float16)Wl[64 + dd + 1]};
            bbp[d2] = h2{(_Float16)bl[dd],      (_Float16)bl[dd + 1]};
        }

        const h2 ninf2 = h2{(_Float16)-65504.f, (_Float16)-65504.f};
        h2 gm[3][4];
        #pragma unroll
        for (int gg = 0; gg < 3; ++gg)
            #pragma unroll
            for (int d2 = 0; d2 < 4; ++d2) gm[gg][d2] = ninf2;

        constexpr int GT4[4][8] = {
            {2,2,2,2,2,2,2,2},
            {2,2,2,2,2,2,2,2},
            {2,2,1,1,1,1,2,2},
            {2,2,1,0,0,1,2,2},
        };

        #pragma unroll
        for (int pi = 0; pi < 4; ++pi) {
            const int prow = h ? (7 - pi) : pi;
            // fp16 idx: prow*768 + ln*24 (byte prow*1536 + ln*48, 16B-aligned)
            const int base = prow * 768 + ln * 24;
            union { h8 v[3]; _Float16 e[24]; } u;
            u.v[0] = *(const h8*)&sP[base];
            u.v[1] = *(const h8*)&sP[base + 8];
            u.v[2] = *(const h8*)&sP[base + 16];
            #pragma unroll
            for (int pj = 0; pj < 8; ++pj) {
                const int grp = GT4[pi][pj];
                const _Float16 x = u.e[pj*3];
                const _Float16 y = u.e[pj*3+1];
                const _Float16 z = u.e[pj*3+2];
                #pragma unroll
                for (int d2 = 0; d2 < 4; ++d2) {
                    h2 v = x * w0p[d2] + bbp[d2];     // v_pk_fma_f16
                    v = y * w1p[d2] + v;
                    v = z * w2p[d2] + v;
                    gm[grp][d2] = __builtin_elementwise_max(gm[grp][d2], v);
                }
            }
        }
        // combine mirrored row-halves (t and t^4 same wave), then leaky + store
        #pragma unroll
        for (int gg = 0; gg < 3; ++gg)
            #pragma unroll
            for (int d2 = 0; d2 < 4; ++d2)
                gm[gg][d2] = h2max_x4(gm[gg][d2]);

        if (h == 0) {
            const _Float16 c02 = (_Float16)0.2f;
            #pragma unroll
            for (int gg = 0; gg < 3; ++gg) {
                union { h8 v; h2 p[4]; } uo;
                #pragma unroll
                for (int d2 = 0; d2 < 4; ++d2) {
                    const h2 g2 = gm[gg][d2];
                    uo.p[d2] = __builtin_elementwise_max(g2, g2 * c02);   // leaky 0.2
                }
                *(h8*)&sV[ln*SVH + gg*32 + dq] = uo.v;
            }
        }
    }
    __syncthreads();   // barrier 1: V ready

    // -- build P2 B-frags + bias (consumed after barrier 2; hidden by phase 1)
    h8 Bf2[4];
    #pragma unroll
    for (int kq = 0; kq < 4; ++kq)
        Bf2[kq] = bfrag(W1, 64, kq*32 + k8, wv*16 + l15);
    const float b1v = b1[wv*16 + l15];

    // ===== Phase 1 (MFMA): C = leaky(V[32,96] @ Wc + bc) =====
    {
        f4 acc[2][2];
        #pragma unroll
        for (int mt = 0; mt < 2; ++mt)
            #pragma unroll
            for (int nn = 0; nn < 2; ++nn) {
                f4 z = {bcv[nn], bcv[nn], bcv[nn], bcv[nn]};
                acc[mt][nn] = z;
            }
        #pragma unroll
        for (int mt = 0; mt < 2; ++mt)
            #pragma unroll
            for (int kq = 0; kq < 3; ++kq) {
                const h8 Af = *(const h8*)&sV[(mt*16 + l15)*SVH + kq*32 + lq*8];
                acc[mt][0] = __builtin_amdgcn_mfma_f32_16x16x32_f16(Af, Bf1[0][kq], acc[mt][0], 0, 0, 0);
                acc[mt][1] = __builtin_amdgcn_mfma_f32_16x16x32_f16(Af, Bf1[1][kq], acc[mt][1], 0, 0, 0);
            }
        // epilogue straight into sC (disjoint from sV -> no extra barrier)
        #pragma unroll
        for (int mt = 0; mt < 2; ++mt)
            #pragma unroll
            for (int nn = 0; nn < 2; ++nn) {
                const int col = (wv*2 + nn)*16 + l15;
                #pragma unroll
                for (int r = 0; r < 4; ++r) {
                    const int row = mt*16 + lq*4 + r;
                    const float v = acc[mt][nn][r];
                    sC[row*SCH + col] = (_Float16)fmaxf(v, 0.2f * v);
                }
            }
    }
    __syncthreads();   // barrier 2: C ready (and all V reads done)

    // -- build P3/P4 B-frags + biases + W4 (consumed after barriers 3/4)
    h8 Bf3[2];
    #pragma unroll
    for (int kq = 0; kq < 2; ++kq)
        Bf3[kq] = bfrag(W2, 32, kq*32 + k8, (wv >> 1)*16 + l15);
    const h8 Bf4 = bfrag(W3, 16, k8, l15);
    const float b2v = b2[(wv >> 1)*16 + l15];
    const float b3v = b3[l15];
    float w4c[3];
    #pragma unroll
    for (int c = 0; c < 3; ++c) w4c[c] = W4[l15*3 + c];

    // ===== Phase 2 (MFMA): H1 = relu(C[32,128] @ W1 + b1) =====
    {
        f4 acc[2];
        #pragma unroll
        for (int mt = 0; mt < 2; ++mt) { f4 z = {b1v,b1v,b1v,b1v}; acc[mt] = z; }
        #pragma unroll
        for (int mt = 0; mt < 2; ++mt)
            #pragma unroll
            for (int kq = 0; kq < 4; ++kq) {
                const h8 Af = *(const h8*)&sC[(mt*16 + l15)*SCH + kq*32 + lq*8];
                acc[mt] = __builtin_amdgcn_mfma_f32_16x16x32_f16(Af, Bf2[kq], acc[mt], 0, 0, 0);
            }
        // epilogue into sV (H1): V reads all completed before barrier 2
        #pragma unroll
        for (int mt = 0; mt < 2; ++mt) {
            const int col = wv*16 + l15;
            #pragma unroll
            for (int r = 0; r < 4; ++r) {
                const int row = mt*16 + lq*4 + r;
                sV[row*S1H + col] = (_Float16)fmaxf(acc[mt][r], 0.f);
            }
        }
    }
    __syncthreads();   // barrier 3: H1 ready (and all C reads done)

    // ===== Phase 3 (MFMA): H2 = relu(H1[32,64] @ W2 + b2) =====
    {
        const int mt = wv & 1;
        const int nt = wv >> 1;
        f4 acc = {b2v, b2v, b2v, b2v};
        #pragma unroll
        for (int kq = 0; kq < 2; ++kq) {
            const h8 Af = *(const h8*)&sV[(mt*16 + l15)*S1H + kq*32 + lq*8];
            acc = __builtin_amdgcn_mfma_f32_16x16x32_f16(Af, Bf3[kq], acc, 0, 0, 0);
        }
        // epilogue into sC (H2 region): C reads done before barrier 3
        const int col = nt*16 + l15;
        #pragma unroll
        for (int r = 0; r < 4; ++r) {
            const int row = mt*16 + lq*4 + r;
            sC[row*S2H + col] = (_Float16)fmaxf(acc[r], 0.f);
        }
    }
    __syncthreads();   // barrier 4: H2 ready

    // ===== Phase 4+5 fused: H3 = relu(H2 @ W3 + b3); out = H3 @ W4 + b4 =====
    if (wv < 2) {
        f4 acc = {b3v, b3v, b3v, b3v};
        const h8 Af = *(const h8*)&sC[(wv*16 + l15)*S2H + lq*8];
        acc = __builtin_amdgcn_mfma_f32_16x16x32_f16(Af, Bf4, acc, 0, 0, 0);
        #pragma unroll
        for (int r = 0; r < 4; ++r) {
            const float h3 = fmaxf(acc[r], 0.f);    // H3[row][l15], row = wv*16+lq*4+r
            #pragma unroll
            for (int c = 0; c < 3; ++c) {
                float p = h3 * w4c[c];
                p += __shfl_xor(p, 1);
                p += __shfl_xor(p, 2);
                p += __shfl_xor(p, 4);
                p += __shfl_xor(p, 8);
                if (l15 == c) {
                    const int gn = blk*32 + wv*16 + lq*4 + r;
                    out[gn*3 + c] = p + b4[c];
                }
            }
        }
    }
}

extern "C" void kernel_launch(void* const* d_in, const int* in_sizes, int n_in,
                              void* d_out, int out_size, void* d_ws, size_t ws_size,
                              hipStream_t stream)
{
    const float* pgi = (const float*)d_in[0];
    const float* Wl  = (const float*)d_in[1];
    const float* bl  = (const float*)d_in[2];
    const float* Wc  = (const float*)d_in[3];
    const float* bc  = (const float*)d_in[4];
    const float* W1  = (const float*)d_in[5];
    const float* b1  = (const float*)d_in[6];
    const float* W2  = (const float*)d_in[7];
    const float* b2  = (const float*)d_in[8];
    const float* W3  = (const float*)d_in[9];
    const float* b3  = (const float*)d_in[10];
    const float* W4  = (const float*)d_in[11];
    const float* b4  = (const float*)d_in[12];

    hipLaunchKernelGGL(flatnet_fused, dim3(1024), dim3(256), 0, stream,
                       pgi, Wl, bl, Wc, bc, W1, b1, W2, b2, W3, b3, W4, b4,
                       (float*)d_out);
}